// Round 12
// baseline (182.845 us; speedup 1.0000x reference)
//
#include <hip/hip_runtime.h>
#include <hip/hip_bf16.h>
#include <cstddef>
#include <cstdint>

#define BB 16
#define SS 4096
#define DD 2048
#define AA 2048
#define ACH 64         // a-chunks for vpart
#define RPB 32         // rows per fused block
#define CHB 128        // fused block-partials per batch = SS/RPB

#define AS1 __attribute__((address_space(1)))
#define AS3 __attribute__((address_space(3)))

// async global->LDS, 16B per lane, dest = wave-uniform base + lane*16
__device__ __forceinline__ void gll16(const float* g, float* l) {
  __builtin_amdgcn_global_load_lds((const AS1 uint32_t*)g, (AS3 uint32_t*)l, 16, 0, 0);
}

__device__ inline unsigned int pk_bf16(float a, float b) {
  __hip_bfloat162 h2 = __float22bfloat162_rn(make_float2(a, b));
  return *reinterpret_cast<unsigned int*>(&h2);
}

// ---------------- kernel 1: hp[b,a] = hid[b,:]·W[a,:] + bias[a] ----------------
__global__ __launch_bounds__(256) void hp_kernel(
    const float* __restrict__ hid, const float* __restrict__ W,
    const float* __restrict__ bias, float* __restrict__ hp) {
  int gw   = (blockIdx.x * 256 + threadIdx.x) >> 6;  // a
  int lane = threadIdx.x & 63;
  int a = gw;
  const float4* Wr = reinterpret_cast<const float4*>(W + (size_t)a * DD);
  float acc[BB];
#pragma unroll
  for (int b = 0; b < BB; ++b) acc[b] = 0.f;
#pragma unroll
  for (int k = 0; k < 8; ++k) {
    float4 w4 = Wr[lane + 64 * k];
#pragma unroll
    for (int b = 0; b < BB; ++b) {
      float4 h4 = reinterpret_cast<const float4*>(hid + b * DD)[lane + 64 * k];
      acc[b] += w4.x * h4.x + w4.y * h4.y + w4.z * h4.z + w4.w * h4.w;
    }
  }
  float bi = bias[a];
#pragma unroll
  for (int b = 0; b < BB; ++b) {
    float s = acc[b];
#pragma unroll
    for (int off = 32; off; off >>= 1) s += __shfl_xor(s, off, 64);
    if (lane == 0) hp[b * AA + a] = s + bi;
  }
}

// ---------------- kernel 2: vpart[ac][b][d] = sum over a-chunk of hp[b,a]*W[a,d] ----------------
__global__ __launch_bounds__(256) void vpart_kernel(
    const float* __restrict__ hp, const float* __restrict__ W,
    float* __restrict__ vpart) {
  int t  = threadIdx.x;
  int ac = blockIdx.x & 63;
  int dc = blockIdx.x >> 6;
  int d0 = dc * 1024 + 4 * t;
  float4 acc[BB];
#pragma unroll
  for (int b = 0; b < BB; ++b) acc[b] = make_float4(0.f, 0.f, 0.f, 0.f);
  int abase = ac * 32;
  for (int i = 0; i < 32; ++i) {
    int a = abase + i;
    float4 w4 = *reinterpret_cast<const float4*>(W + (size_t)a * DD + d0);
#pragma unroll
    for (int b = 0; b < BB; ++b) {
      float h = hp[b * AA + a];  // wave-uniform -> scalar load
      acc[b].x += h * w4.x; acc[b].y += h * w4.y;
      acc[b].z += h * w4.z; acc[b].w += h * w4.w;
    }
  }
#pragma unroll
  for (int b = 0; b < BB; ++b)
    *reinterpret_cast<float4*>(vpart + (size_t)(ac * BB + b) * DD + d0) = acc[b];
}

// ---------------- kernel 3 (merged): v reduce + c[b] ----------------
__global__ __launch_bounds__(256) void finalize_kernel(
    const float* __restrict__ vpart, const float* __restrict__ hp,
    const float* __restrict__ bias, float* __restrict__ v,
    float* __restrict__ cvec) {
  if (blockIdx.x < 128) {
    int i = blockIdx.x * 256 + threadIdx.x;  // i = b*DD + d
    float s = 0.f;
#pragma unroll
    for (int c = 0; c < ACH; ++c) s += vpart[(size_t)c * (BB * DD) + i];
    v[i] = s;
  } else {
    int b = blockIdx.x - 128;
    int t = threadIdx.x;
    float s = 0.f;
    for (int i = t; i < AA; i += 256) s += bias[i] * hp[b * AA + i];
#pragma unroll
    for (int off = 32; off; off >>= 1) s += __shfl_xor(s, off, 64);
    __shared__ float red[4];
    if ((t & 63) == 0) red[t >> 6] = s;
    __syncthreads();
    if (t == 0) cvec[b] = red[0] + red[1] + red[2] + red[3];
  }
}

// ---------------- kernel 4 (FUSED): one HBM pass over enc ----------------
// EXACT R9 schedule, but RPB=32 with grid 2048 -> 6 blocks/CU resident
// (24 waves/CU, +50% TLP vs R9's 16). 3-slot LDS pipeline (24KB), lag-1
// score pipeline, one barrier per row, depth-2 per-wave counted vmcnt(2),
// peeled tail. Each wave stages AND reads only its quarter-row.
__global__ void fused_kernel(
    const float* __restrict__ enc, const float* __restrict__ v,
    const float* __restrict__ cvec, float* __restrict__ scores,
    float* __restrict__ mpart, float* __restrict__ lpart,
    unsigned int* __restrict__ ctxpart /* packed bf16x2 */) {
  __shared__ float rowbuf[3][DD];      // 24KB; wave wv owns floats [wv*512, wv*512+512)
  __shared__ float red[2][4];
  int tid  = threadIdx.x;
  int wv   = tid >> 6;
  int lane = tid & 63;
  int blk  = blockIdx.x;               // 2048 blocks = 32 rows each
  int b    = blk >> 7;                 // 128 chunks per batch
  size_t row0 = (size_t)b * SS + (size_t)(blk & 127) * RPB;
  const float* rbase = enc + row0 * DD;
  int gofs = wv * 512 + lane * 4;

#define STAGE(rn, slot)                                                      \
  do {                                                                       \
    gll16(rbase + (size_t)(rn) * DD + gofs,       &rowbuf[slot][wv * 512]);  \
    gll16(rbase + (size_t)(rn) * DD + gofs + 256, &rowbuf[slot][wv * 512 + 256]); \
  } while (0)

  // v cols [8t,8t+8) in registers; force arrival before glls so vmcnt
  // counting over glls stays exact.
  float4 va = *reinterpret_cast<const float4*>(v + (size_t)b * DD + 8 * tid);
  float4 vb = *reinterpret_cast<const float4*>(v + (size_t)b * DD + 8 * tid + 4);
  float cb = cvec[b];
  asm volatile("s_waitcnt vmcnt(0)" ::: "memory");

  STAGE(0, 0);
  STAGE(1, 1);

  float4 a0 = make_float4(0.f, 0.f, 0.f, 0.f);
  float4 a1 = make_float4(0.f, 0.f, 0.f, 0.f);
  float4 ep0 = a0, ep1 = a1;
  float m_s = -1e30f, l = 0.f, myscore = 0.f;

#pragma unroll 3
  for (int r = 0; r < RPB - 1; ++r) {
    asm volatile("s_waitcnt vmcnt(2)" ::: "memory");   // row r landed (this wave's quarter)
    asm volatile("s_waitcnt lgkmcnt(0)" ::: "memory"); // red[r-1] write retired
    __builtin_amdgcn_s_barrier();
    __builtin_amdgcn_sched_barrier(0);
    if (r + 2 < RPB) STAGE(r + 2, (r + 2) % 3);        // slot held row r-1: regs already

    const float4* rp = reinterpret_cast<const float4*>(&rowbuf[r % 3][0]);
    float4 e0 = rp[2 * tid];
    float4 e1 = rp[2 * tid + 1];
    float pd = e0.x * va.x + e0.y * va.y + e0.z * va.z + e0.w * va.w +
               e1.x * vb.x + e1.y * vb.y + e1.z * vb.z + e1.w * vb.w;
#pragma unroll
    for (int off = 32; off; off >>= 1) pd += __shfl_xor(pd, off, 64);
    if (lane == 0) red[r & 1][wv] = pd;

    if (r > 0) {  // consume score of row r-1 (red visible since this iter's barrier)
      float score = ((red[(r - 1) & 1][0] + red[(r - 1) & 1][1]) +
                     (red[(r - 1) & 1][2] + red[(r - 1) & 1][3])) + cb;
      if (tid == r - 1) myscore = score;
      if (score > m_s + 40.f) {          // block-uniform, rare
        float rs = __expf(m_s - score);  // 0 on first row (acc is 0 anyway)
        l *= rs;
        a0.x *= rs; a0.y *= rs; a0.z *= rs; a0.w *= rs;
        a1.x *= rs; a1.y *= rs; a1.z *= rs; a1.w *= rs;
        m_s = score;
      }
      float p = __expf(score - m_s);     // <= e^40, f32-safe
      l += p;
      a0.x += p * ep0.x; a0.y += p * ep0.y; a0.z += p * ep0.z; a0.w += p * ep0.w;
      a1.x += p * ep1.x; a1.y += p * ep1.y; a1.z += p * ep1.z; a1.w += p * ep1.w;
    }
    ep0 = e0; ep1 = e1;
  }

  // ---- tail: last row dot + final two scores ----
  asm volatile("s_waitcnt vmcnt(0)" ::: "memory");
  asm volatile("s_waitcnt lgkmcnt(0)" ::: "memory");
  __builtin_amdgcn_s_barrier();
  __builtin_amdgcn_sched_barrier(0);
  {
    const float4* rp = reinterpret_cast<const float4*>(&rowbuf[(RPB - 1) % 3][0]);
    float4 e0 = rp[2 * tid];
    float4 e1 = rp[2 * tid + 1];
    float pd = e0.x * va.x + e0.y * va.y + e0.z * va.z + e0.w * va.w +
               e1.x * vb.x + e1.y * vb.y + e1.z * vb.z + e1.w * vb.w;
#pragma unroll
    for (int off = 32; off; off >>= 1) pd += __shfl_xor(pd, off, 64);
    if (lane == 0) red[(RPB - 1) & 1][wv] = pd;

    // score row RPB-2 (parity (RPB-2)&1 = 0 for even RPB)
    float score = ((red[0][0] + red[0][1]) + (red[0][2] + red[0][3])) + cb;
    if (tid == RPB - 2) myscore = score;
    if (score > m_s + 40.f) {
      float rs = __expf(m_s - score);
      l *= rs;
      a0.x *= rs; a0.y *= rs; a0.z *= rs; a0.w *= rs;
      a1.x *= rs; a1.y *= rs; a1.z *= rs; a1.w *= rs;
      m_s = score;
    }
    float p = __expf(score - m_s);
    l += p;
    a0.x += p * ep0.x; a0.y += p * ep0.y; a0.z += p * ep0.z; a0.w += p * ep0.w;
    a1.x += p * ep1.x; a1.y += p * ep1.y; a1.z += p * ep1.z; a1.w += p * ep1.w;
    ep0 = e0; ep1 = e1;

    asm volatile("s_waitcnt lgkmcnt(0)" ::: "memory");
    __builtin_amdgcn_s_barrier();
    // score row RPB-1 (parity 1)
    float score2 = ((red[1][0] + red[1][1]) + (red[1][2] + red[1][3])) + cb;
    if (tid == RPB - 1) myscore = score2;
    if (score2 > m_s + 40.f) {
      float rs = __expf(m_s - score2);
      l *= rs;
      a0.x *= rs; a0.y *= rs; a0.z *= rs; a0.w *= rs;
      a1.x *= rs; a1.y *= rs; a1.z *= rs; a1.w *= rs;
      m_s = score2;
    }
    float p2 = __expf(score2 - m_s);
    l += p2;
    a0.x += p2 * ep0.x; a0.y += p2 * ep0.y; a0.z += p2 * ep0.z; a0.w += p2 * ep0.w;
    a1.x += p2 * ep1.x; a1.y += p2 * ep1.y; a1.z += p2 * ep1.z; a1.w += p2 * ep1.w;
  }
#undef STAGE

  if (tid < RPB) scores[row0 + tid] = myscore;
  if (tid == 0) { mpart[blk] = m_s; lpart[blk] = l; }
  uint4 u;
  u.x = pk_bf16(a0.x, a0.y);
  u.y = pk_bf16(a0.z, a0.w);
  u.z = pk_bf16(a1.x, a1.y);
  u.w = pk_bf16(a1.z, a1.w);
  reinterpret_cast<uint4*>(ctxpart)[(size_t)blk * 256 + tid] = u;
}

// ---------------- kernel 5 (merged epilogue): weights + weighted combine ----------------
// block = (b, dslice of 256 cols). CHB=128 chunks per b. Threads 0..127 own
// one chunk each (upper half duplicates for max, contributes 0 to sum);
// 4-wave LDS combine for M and L; then per-column weighted reduce.
__global__ __launch_bounds__(256) void epilogue_kernel(
    const float* __restrict__ mpart, const float* __restrict__ lpart,
    const unsigned int* __restrict__ ctxpart, float* __restrict__ ctx) {
  int b  = blockIdx.x >> 3;
  int ds = blockIdx.x & 7;
  int t  = threadIdx.x;
  __shared__ float wsm[CHB];
  __shared__ float redm[4], redl[4];
  int c = t & (CHB - 1);
  float mt = mpart[b * CHB + c];
  float lt = (t < CHB) ? lpart[b * CHB + c] : 0.f;
  float M = mt;
#pragma unroll
  for (int off = 32; off; off >>= 1) M = fmaxf(M, __shfl_xor(M, off, 64));
  if ((t & 63) == 0) redm[t >> 6] = M;
  __syncthreads();
  M = fmaxf(fmaxf(redm[0], redm[1]), fmaxf(redm[2], redm[3]));
  float w  = __expf(mt - M);
  float lw = lt * w;   // 0 for t >= CHB
#pragma unroll
  for (int off = 32; off; off >>= 1) lw += __shfl_xor(lw, off, 64);
  if ((t & 63) == 0) redl[t >> 6] = lw;
  __syncthreads();
  float L = redl[0] + redl[1] + redl[2] + redl[3];
  if (t < CHB) wsm[t] = w / L;
  __syncthreads();
  int du = ds * 128 + (t >> 1);   // uint index within a chunk row
  bool hi = (t & 1);
  float acc = 0.f;
  const unsigned int* base = ctxpart + (size_t)b * CHB * (DD / 2) + du;
  for (int cc = 0; cc < CHB; ++cc) {
    unsigned int u = base[(size_t)cc * (DD / 2)];
    float e = __uint_as_float(hi ? (u & 0xffff0000u) : (u << 16));
    acc += wsm[cc] * e;
  }
  ctx[b * DD + ds * 256 + t] = acc;
}

extern "C" void kernel_launch(void* const* d_in, const int* in_sizes, int n_in,
                              void* d_out, int out_size, void* d_ws, size_t ws_size,
                              hipStream_t stream) {
  const float* enc  = (const float*)d_in[0];  // [B,S,D]
  const float* hid  = (const float*)d_in[1];  // [B,D]
  const float* W    = (const float*)d_in[2];  // [A,D]
  const float* bias = (const float*)d_in[3];  // [A]

  float* out_scores = (float*)d_out;            // [B,S]
  float* out_ctx    = (float*)d_out + BB * SS;  // [B,D]

  float* ws    = (float*)d_ws;
  float* hp    = ws;                        // B*A        = 32768 f
  float* vpart = hp + BB * AA;              // ACH*B*D    = 2097152 f
  float* v     = vpart + ACH * BB * DD;     // B*D        = 32768 f
  float* cvec  = v + BB * DD;               // B          = 16 f
  float* mpart = cvec + BB;                 // B*CHB      = 2048 f
  float* lpart = mpart + BB * CHB;          // B*CHB      = 2048 f
  unsigned int* ctxp = (unsigned int*)(lpart + BB * CHB);  // B*CHB*D bf16 = 8 MB
  // total ~17 MB

  hipLaunchKernelGGL(hp_kernel,       dim3(512),  dim3(256), 0, stream, hid, W, bias, hp);
  hipLaunchKernelGGL(vpart_kernel,    dim3(128),  dim3(256), 0, stream, hp, W, vpart);
  hipLaunchKernelGGL(finalize_kernel, dim3(144),  dim3(256), 0, stream, vpart, hp, bias, v, cvec);
  hipLaunchKernelGGL(fused_kernel,    dim3(2048), dim3(256), 0, stream,
                     enc, v, cvec, out_scores, mpart, lpart, ctxp);
  hipLaunchKernelGGL(epilogue_kernel, dim3(128),  dim3(256), 0, stream,
                     mpart, lpart, ctxp, out_ctx);
}

// Round 14
// 170.726 us; speedup vs baseline: 1.0710x; 1.0710x over previous
//
#include <hip/hip_runtime.h>
#include <hip/hip_bf16.h>
#include <cstddef>
#include <cstdint>

#define BB 16
#define SS 4096
#define DD 2048
#define AA 2048
#define ACH 64         // a-chunks for vpart
#define RPB 64         // rows per fused block
#define CHB 64         // fused chunks per batch = SS/RPB

#define AS1 __attribute__((address_space(1)))
#define AS3 __attribute__((address_space(3)))

// async global->LDS, 16B per lane, dest = wave-uniform base + lane*16
__device__ __forceinline__ void gll16(const float* g, float* l) {
  __builtin_amdgcn_global_load_lds((const AS1 uint32_t*)g, (AS3 uint32_t*)l, 16, 0, 0);
}

__device__ inline unsigned int pk_bf16(float a, float b) {
  __hip_bfloat162 h2 = __float22bfloat162_rn(make_float2(a, b));
  return *reinterpret_cast<unsigned int*>(&h2);
}

// ---------------- kernel 1: hp[b,a] = hid[b,:]·W[a,:] + bias[a] ----------------
__global__ __launch_bounds__(256) void hp_kernel(
    const float* __restrict__ hid, const float* __restrict__ W,
    const float* __restrict__ bias, float* __restrict__ hp) {
  int gw   = (blockIdx.x * 256 + threadIdx.x) >> 6;  // a
  int lane = threadIdx.x & 63;
  int a = gw;
  const float4* Wr = reinterpret_cast<const float4*>(W + (size_t)a * DD);
  float acc[BB];
#pragma unroll
  for (int b = 0; b < BB; ++b) acc[b] = 0.f;
#pragma unroll
  for (int k = 0; k < 8; ++k) {
    float4 w4 = Wr[lane + 64 * k];
#pragma unroll
    for (int b = 0; b < BB; ++b) {
      float4 h4 = reinterpret_cast<const float4*>(hid + b * DD)[lane + 64 * k];
      acc[b] += w4.x * h4.x + w4.y * h4.y + w4.z * h4.z + w4.w * h4.w;
    }
  }
  float bi = bias[a];
#pragma unroll
  for (int b = 0; b < BB; ++b) {
    float s = acc[b];
#pragma unroll
    for (int off = 32; off; off >>= 1) s += __shfl_xor(s, off, 64);
    if (lane == 0) hp[b * AA + a] = s + bi;
  }
}

// ---------------- kernel 2: vpart[ac][b][d] = sum over a-chunk of hp[b,a]*W[a,d] ----------------
__global__ __launch_bounds__(256) void vpart_kernel(
    const float* __restrict__ hp, const float* __restrict__ W,
    float* __restrict__ vpart) {
  int t  = threadIdx.x;
  int ac = blockIdx.x & 63;
  int dc = blockIdx.x >> 6;
  int d0 = dc * 1024 + 4 * t;
  float4 acc[BB];
#pragma unroll
  for (int b = 0; b < BB; ++b) acc[b] = make_float4(0.f, 0.f, 0.f, 0.f);
  int abase = ac * 32;
  for (int i = 0; i < 32; ++i) {
    int a = abase + i;
    float4 w4 = *reinterpret_cast<const float4*>(W + (size_t)a * DD + d0);
#pragma unroll
    for (int b = 0; b < BB; ++b) {
      float h = hp[b * AA + a];  // wave-uniform -> scalar load
      acc[b].x += h * w4.x; acc[b].y += h * w4.y;
      acc[b].z += h * w4.z; acc[b].w += h * w4.w;
    }
  }
#pragma unroll
  for (int b = 0; b < BB; ++b)
    *reinterpret_cast<float4*>(vpart + (size_t)(ac * BB + b) * DD + d0) = acc[b];
}

// ---------------- kernel 3 (merged): v reduce + c[b] ----------------
__global__ __launch_bounds__(256) void finalize_kernel(
    const float* __restrict__ vpart, const float* __restrict__ hp,
    const float* __restrict__ bias, float* __restrict__ v,
    float* __restrict__ cvec) {
  if (blockIdx.x < 128) {
    int i = blockIdx.x * 256 + threadIdx.x;  // i = b*DD + d
    float s = 0.f;
#pragma unroll
    for (int c = 0; c < ACH; ++c) s += vpart[(size_t)c * (BB * DD) + i];
    v[i] = s;
  } else {
    int b = blockIdx.x - 128;
    int t = threadIdx.x;
    float s = 0.f;
    for (int i = t; i < AA; i += 256) s += bias[i] * hp[b * AA + i];
#pragma unroll
    for (int off = 32; off; off >>= 1) s += __shfl_xor(s, off, 64);
    __shared__ float red[4];
    if ((t & 63) == 0) red[t >> 6] = s;
    __syncthreads();
    if (t == 0) cvec[b] = red[0] + red[1] + red[2] + red[3];
  }
}

// ---------------- kernel 4 (FUSED): one HBM pass over enc ----------------
// Block = 64 contiguous rows. 3-slot LDS row pipeline fed by global_load_lds:
// loads issued 2 rows ahead, counted s_waitcnt vmcnt(2), RAW s_barrier (NOT
// __syncthreads - its vmcnt(0) would drain the pipeline). Thread t owns cols
// [8t,8t+8): dot partial (8 FMA) -> wave shfl reduce -> 4-entry LDS combine ->
// block-uniform score; deferred-rescale online-softmax acc (8 VGPR).
// All in-loop VMEM is global_load_lds => vmcnt counting is exact.
__global__ void fused_kernel(
    const float* __restrict__ enc, const float* __restrict__ v,
    const float* __restrict__ cvec, float* __restrict__ scores,
    float* __restrict__ mpart, float* __restrict__ lpart,
    unsigned int* __restrict__ ctxpart /* packed bf16x2 */) {
  __shared__ float rowbuf[3][DD];
  __shared__ float vsh[DD];
  __shared__ float red[4];
  int tid  = threadIdx.x;
  int wv   = tid >> 6;
  int lane = tid & 63;
  int blk  = blockIdx.x;            // 1024 blocks
  int b    = blk >> 6;
  int c64  = blk & 63;
  size_t row0 = (size_t)b * SS + (size_t)c64 * RPB;   // flat row index
  const float* rbase = enc + row0 * DD;
  int gofs = wv * 512 + lane * 4;   // this lane's float offset within a 2KB wave-segment pair

  // ---- prologue: stage v, issue rows 0,1 (6 gll outstanding) ----
  gll16(v + (size_t)b * DD + gofs,        &vsh[wv * 512]);
  gll16(v + (size_t)b * DD + gofs + 256,  &vsh[wv * 512 + 256]);
  gll16(rbase + gofs,        &rowbuf[0][wv * 512]);
  gll16(rbase + gofs + 256,  &rowbuf[0][wv * 512 + 256]);
  gll16(rbase + DD + gofs,       &rowbuf[1][wv * 512]);
  gll16(rbase + DD + gofs + 256, &rowbuf[1][wv * 512 + 256]);
  asm volatile("s_waitcnt vmcnt(4)" ::: "memory");   // v landed
  __builtin_amdgcn_s_barrier();
  __builtin_amdgcn_sched_barrier(0);

  const float4* vs4 = reinterpret_cast<const float4*>(vsh);
  float4 va = vs4[2 * tid];
  float4 vb = vs4[2 * tid + 1];
  float cb = cvec[b];

  float4 a0 = make_float4(0.f, 0.f, 0.f, 0.f);
  float4 a1 = make_float4(0.f, 0.f, 0.f, 0.f);
  float m_s = -1e30f, l = 0.f, myscore = 0.f;
  int slot = 0, islot = 2;

  for (int r = 0; r < RPB; ++r) {
    // row r resident in rowbuf[slot]; rows r+1 in flight (2 gll outstanding)
    asm volatile("s_waitcnt vmcnt(2)" ::: "memory");
    __builtin_amdgcn_s_barrier();
    __builtin_amdgcn_sched_barrier(0);

    const float4* rp = reinterpret_cast<const float4*>(&rowbuf[slot][0]);
    float4 ra = rp[2 * tid];
    float4 rb = rp[2 * tid + 1];

    // issue row r+2 into islot (its previous contents consumed at r-1, fenced
    // by the barrier above). Tail: clamped dummy re-read of row 63 into a
    // slot nobody reads -> uniform vmcnt(2) every iteration.
    {
      int rn = (r + 2 < RPB) ? r + 2 : (RPB - 1);
      const float* g = rbase + (size_t)rn * DD + gofs;
      gll16(g,       &rowbuf[islot][wv * 512]);
      gll16(g + 256, &rowbuf[islot][wv * 512 + 256]);
    }

    float pd = ra.x * va.x + ra.y * va.y + ra.z * va.z + ra.w * va.w +
               rb.x * vb.x + rb.y * vb.y + rb.z * vb.z + rb.w * vb.w;
#pragma unroll
    for (int off = 32; off; off >>= 1) pd += __shfl_xor(pd, off, 64);
    if (lane == 0) red[wv] = pd;
    asm volatile("s_waitcnt lgkmcnt(0)" ::: "memory");
    __builtin_amdgcn_s_barrier();
    __builtin_amdgcn_sched_barrier(0);
    float score = ((red[0] + red[1]) + (red[2] + red[3])) + cb;  // block-uniform
    if (tid == r) myscore = score;

    if (score > m_s + 40.f) {          // uniform branch, rare
      float rs = __expf(m_s - score);  // 0 on first row (acc is 0 anyway)
      l *= rs;
      a0.x *= rs; a0.y *= rs; a0.z *= rs; a0.w *= rs;
      a1.x *= rs; a1.y *= rs; a1.z *= rs; a1.w *= rs;
      m_s = score;
    }
    float p = __expf(score - m_s);     // <= e^40, f32-safe
    l += p;
    a0.x += p * ra.x; a0.y += p * ra.y; a0.z += p * ra.z; a0.w += p * ra.w;
    a1.x += p * rb.x; a1.y += p * rb.y; a1.z += p * rb.z; a1.w += p * rb.w;

    slot  = (slot  == 2) ? 0 : slot + 1;
    islot = (islot == 2) ? 0 : islot + 1;
  }

  // drain dummy gll's before any wave can exit (LDS freed at block end)
  asm volatile("s_waitcnt vmcnt(0)" ::: "memory");

  if (tid < RPB) scores[row0 + tid] = myscore;
  if (tid == 0) { mpart[blk] = m_s; lpart[blk] = l; }
  uint4 u;
  u.x = pk_bf16(a0.x, a0.y);
  u.y = pk_bf16(a0.z, a0.w);
  u.z = pk_bf16(a1.x, a1.y);
  u.w = pk_bf16(a1.z, a1.w);
  reinterpret_cast<uint4*>(ctxpart)[(size_t)blk * 256 + tid] = u;
}

// ---------------- kernel 5 (merged epilogue): weights + weighted combine ----------------
// block = (b, dslice of 256 cols). CHB=64 chunks per b; every wave spans all
// 64 chunks via (t&63), so the m/l reduction is wave-local (identical in all
// waves). Then ctx[b,col] = sum_c w[c] * ctxpart[b,c,col].
__global__ __launch_bounds__(256) void epilogue_kernel(
    const float* __restrict__ mpart, const float* __restrict__ lpart,
    const unsigned int* __restrict__ ctxpart, float* __restrict__ ctx) {
  int b  = blockIdx.x >> 3;
  int ds = blockIdx.x & 7;
  int t  = threadIdx.x;
  __shared__ float wsm[CHB];
  int c = t & 63;
  float mt = mpart[b * CHB + c];
  float lt = lpart[b * CHB + c];
  float M = mt;
#pragma unroll
  for (int off = 32; off; off >>= 1) M = fmaxf(M, __shfl_xor(M, off, 64));
  float w  = __expf(mt - M);
  float lw = lt * w;
#pragma unroll
  for (int off = 32; off; off >>= 1) lw += __shfl_xor(lw, off, 64);
  if (t < CHB) wsm[t] = w / lw;   // identical values across waves
  __syncthreads();
  int du = ds * 128 + (t >> 1);   // uint index within a chunk row
  bool hi = (t & 1);
  float acc = 0.f;
  const unsigned int* base = ctxpart + (size_t)b * CHB * (DD / 2) + du;
  for (int cc = 0; cc < CHB; ++cc) {
    unsigned int u = base[(size_t)cc * (DD / 2)];
    float e = __uint_as_float(hi ? (u & 0xffff0000u) : (u << 16));
    acc += wsm[cc] * e;
  }
  ctx[b * DD + ds * 256 + t] = acc;
}

extern "C" void kernel_launch(void* const* d_in, const int* in_sizes, int n_in,
                              void* d_out, int out_size, void* d_ws, size_t ws_size,
                              hipStream_t stream) {
  const float* enc  = (const float*)d_in[0];  // [B,S,D]
  const float* hid  = (const float*)d_in[1];  // [B,D]
  const float* W    = (const float*)d_in[2];  // [A,D]
  const float* bias = (const float*)d_in[3];  // [A]

  float* out_scores = (float*)d_out;            // [B,S]
  float* out_ctx    = (float*)d_out + BB * SS;  // [B,D]

  float* ws    = (float*)d_ws;
  float* hp    = ws;                        // B*A        = 32768 f
  float* vpart = hp + BB * AA;              // ACH*B*D    = 2097152 f
  float* v     = vpart + ACH * BB * DD;     // B*D        = 32768 f
  float* cvec  = v + BB * DD;               // B          = 16 f
  float* mpart = cvec + BB;                 // B*CHB      = 1024 f
  float* lpart = mpart + BB * CHB;          // B*CHB      = 1024 f
  unsigned int* ctxp = (unsigned int*)(lpart + BB * CHB);  // B*CHB*D bf16 = 4 MB
  // total ~13 MB

  hipLaunchKernelGGL(hp_kernel,       dim3(512),  dim3(256), 0, stream, hid, W, bias, hp);
  hipLaunchKernelGGL(vpart_kernel,    dim3(128),  dim3(256), 0, stream, hp, W, vpart);
  hipLaunchKernelGGL(finalize_kernel, dim3(144),  dim3(256), 0, stream, vpart, hp, bias, v, cvec);
  hipLaunchKernelGGL(fused_kernel,    dim3(1024), dim3(256), 0, stream,
                     enc, v, cvec, out_scores, mpart, lpart, ctxp);
  hipLaunchKernelGGL(epilogue_kernel, dim3(128),  dim3(256), 0, stream,
                     mpart, lpart, ctxp, out_ctx);
}